// Round 14
// baseline (882.257 us; speedup 1.0000x reference)
//
#include <hip/hip_runtime.h>

typedef unsigned long long u64;
typedef unsigned int u32;
typedef _Float16 f16;
typedef f16 f16x8 __attribute__((ext_vector_type(8)));
typedef float f32x4 __attribute__((ext_vector_type(4)));

#define B_   8
#define C_   256
#define T_   2048
#define NQ   8
#define BINS 1024
#define NROWS (B_ * T_)          // 16384
#define KA   256                 // A: single fp16 limb (row-major [n][256])
#define KB   256                 // B: single fp16 limb (row-major [code][256])
#define NTILE 16                 // 1024 codes / 64 per tile
#define MARGIN 3.0f              // >> worst-case approx error (~0.6) + chop

// ---- workspace layout (bytes) ----
#define XS_OFF   ((size_t)0)                       // f16 [16384][256]   =  8388608
#define CS_OFF   ((size_t)8388608)                 // f16 [8192][256]    =  4194304
#define XT_OFF   ((size_t)12582912)                // f32 [16384][256]   = 16777216
#define C2D_OFF  ((size_t)29360128)                // f64 [8192]         =    65536
#define C2K_OFF  ((size_t)29425664)                // f32 [8192] biased  =    32768
#define IDXI_OFF ((size_t)29458432)                // i32 [131072]       =   524288

static __device__ __forceinline__ void gll16(const void* g, void* l) {
    __builtin_amdgcn_global_load_lds(
        (const __attribute__((address_space(1))) u32*)g,
        (__attribute__((address_space(3))) u32*)l, 16, 0, 0);
}

// ---------------- prep_all: x transpose+cast | cb cast+norms -------------
// grid 3072: bid<1024 -> prep_x tile; bid>=1024 -> prep_cb block (4 codes)
struct alignas(8) H4 { f16 v[4]; };
__global__ __launch_bounds__(256)
void prep_all(const float* __restrict__ x, float* __restrict__ x_t,
              f16* __restrict__ xs, const float* __restrict__ cb,
              f16* __restrict__ cs, double* __restrict__ c2d,
              float* __restrict__ c2k) {
    const int tid = threadIdx.x;
    const int bid = blockIdx.x;
    if (bid < 1024) {
        __shared__ float tile[64][65];
        const int b  = bid >> 7;
        const int c0 = ((bid >> 5) & 3) * 64;
        const int t0 = (bid & 31) * 64;
        {
            const int j = tid & 63, cg = tid >> 6;
            #pragma unroll
            for (int ii = 0; ii < 16; ++ii) {
                const int cl = cg * 16 + ii;
                tile[cl][j] = x[((size_t)(b * C_ + c0 + cl) * T_) + t0 + j];
            }
        }
        __syncthreads();
        {
            const int cl = tid & 63, tg = tid >> 6;
            #pragma unroll
            for (int jj = 0; jj < 16; ++jj) {
                const int tl = tg * 16 + jj;
                const float v = tile[cl][tl];
                const size_t n = (size_t)b * T_ + t0 + tl;
                x_t[n * C_ + c0 + cl] = v;
                xs[n * KA + c0 + cl]  = (f16)v;
            }
        }
    } else {
        const int w    = tid >> 6;
        const int lane = tid & 63;
        const int code = (bid - 1024) * 4 + w;
        const float4 v = *(const float4*)(cb + (size_t)code * C_ + lane * 4);
        H4 h;
        h.v[0] = (f16)v.x; h.v[1] = (f16)v.y;
        h.v[2] = (f16)v.z; h.v[3] = (f16)v.w;
        *(H4*)(cs + (size_t)code * KB + lane * 4) = h;
        double s = (double)v.x * v.x + (double)v.y * v.y +
                   (double)v.z * v.z + (double)v.w * v.w;
        #pragma unroll
        for (int off = 32; off; off >>= 1) s += __shfl_down(s, off, 64);
        if (lane == 0) {
            c2d[code] = s;                    // exact norm (fp64 rescore)
            c2k[code] = (float)s + 1000.0f;   // biased: sc = c2+1000-2xc > 0
        }
    }
}

// ---------------- dist v8: 256-row blocks, m_rep=4, margin-skip ----------
// grid = 64 rt x 8 q = 512 blocks (bid&7 = q -> XCD-local codebook; exactly
// 2 blocks/CU), 1024 threads = 16 waves (4 wr x 4 wc). Each wave: 64 rows
// x K=256 of A in regs (af[4][8] = 128 VGPR; launch_bounds(1024,8) caps
// VGPR at 256 so it stays resident AND 2 blocks/CU fit). Each 16B bg read
// now feeds 4 MFMAs -> per-FLOP LDS reads halved vs r13. B streams thru
// 64-code LDS dbuf, 1 barrier/tile. Biased float-bit keys; per-row top-4
// margin-skipped exact fp64 rescore fused (full-wave-uniform shfls).
__global__ __launch_bounds__(1024, 8)
void dist_kernel(const f16* __restrict__ xs, const f16* __restrict__ cs,
                 const float* __restrict__ c2k, const float* __restrict__ x_t,
                 const float* __restrict__ cb, const double* __restrict__ c2d,
                 float* __restrict__ idx_f, int* __restrict__ idx_i) {
    __shared__ f16 Bs[2][64][256];       // 64 KB
    __shared__ u32 red[256][8];          // 8 KB ([0..3] bins / [4] flag)

    const int tid  = threadIdx.x;
    const int lane = tid & 63;
    const int w    = tid >> 6;           // 0..15
    const int wr   = w >> 2;             // 0..3 row group (64 rows each)
    const int wc   = w & 3;              // 0..3 code column (16 codes/tile)
    const int bid  = blockIdx.x;
    const int q    = bid & 7;
    const int rt   = bid >> 3;
    const int n0   = rt * 256;

    const int c = lane & 15;             // MFMA col / frag row
    const int g = lane >> 4;             // 0..3 k-group

    // ---- A fragments in registers: rows n0 + wr*64 + m*16 + c ----
    f16x8 af[4][8];
    {
        const f16* pa = xs + (size_t)(n0 + wr * 64 + c) * KA + g * 8;
        #pragma unroll
        for (int m = 0; m < 4; ++m)
            #pragma unroll
            for (int kk = 0; kk < 8; ++kk)
                af[m][kk] = *(const f16x8*)(pa + m * 16 * KA + kk * 32);
    }

    // ---- staging: 2 x gll16 per thread per tile ----
    const int crow  = tid >> 5;                    // 0..31 (i=0), +32 (i=1)
    const int slotl = (tid & 31) ^ (crow & 7);     // inverse-swizzled source
    const f16* pb = cs + (size_t)q * 1024 * KB;
    const int wbase = w * 512;                     // uniform dest (f16)

    #define STAGE(buf, t)                                                    \
        do {                                                                 \
            f16* b0 = &Bs[buf][0][0];                                        \
            const f16* s_ = pb + (size_t)((t) * 64 + crow) * KB + slotl * 8; \
            gll16(s_,            b0 + wbase);                                 \
            gll16(s_ + 32 * KB,  b0 + 8192 + wbase);                          \
        } while (0)

    // per-(thread,row) top-2 keys: rows (m, r)
    u32 k1[4][4], k2[4][4];
    #pragma unroll
    for (int m = 0; m < 4; ++m)
        #pragma unroll
        for (int r = 0; r < 4; ++r) { k1[m][r] = ~0u; k2[m][r] = ~0u; }

    const float* c2q = c2k + q * BINS;
    const int rowoff = (wc * 16 + c) * 256;        // B frag row base (f16)
    const int sw = c & 7;

    STAGE(0, 0);
    __syncthreads();

    #pragma unroll 1
    for (int t = 0; t < NTILE; ++t) {
        const int buf = t & 1;
        if (t < NTILE - 1) STAGE(buf ^ 1, t + 1);

        f32x4 acc[4];
        #pragma unroll
        for (int m = 0; m < 4; ++m) {
            f32x4 z = {0.f, 0.f, 0.f, 0.f};
            acc[m] = z;
        }

        const f16* bb = &Bs[buf][0][0] + rowoff;
        #pragma unroll
        for (int half = 0; half < 2; ++half) {
            f16x8 bg[4];
            #pragma unroll
            for (int k4 = 0; k4 < 4; ++k4) {
                const int kk = half * 4 + k4;
                bg[k4] = *(const f16x8*)(bb + ((kk * 4 + g) ^ sw) * 8);
            }
            #pragma unroll
            for (int k4 = 0; k4 < 4; ++k4)
                #pragma unroll
                for (int m = 0; m < 4; ++m)
                    acc[m] = __builtin_amdgcn_mfma_f32_16x16x32_f16(
                        af[m][half * 4 + k4], bg[k4], acc[m], 0, 0, 0);
        }

        // top-2 insert (6 VALU/score): positive floats -> bits monotone
        const int codeL = t * 64 + wc * 16 + c;
        const float cc = c2q[codeL];
        #pragma unroll
        for (int m = 0; m < 4; ++m)
            #pragma unroll
            for (int r = 0; r < 4; ++r) {
                const float sc = fmaf(-2.f, acc[m][r], cc);
                const u32 key = (__float_as_uint(sc) & 0xFFFFFC00u) | (u32)codeL;
                const u32 hi = k1[m][r] > key ? k1[m][r] : key;
                k1[m][r] = k1[m][r] < key ? k1[m][r] : key;
                k2[m][r] = k2[m][r] < hi ? k2[m][r] : hi;
            }

        __syncthreads();   // drains prefetch (vmcnt0) + publishes buf^1
    }
    #undef STAGE

    // ---- merge: 16 lanes (codes) per row -> wave top2 -> red ----
    #pragma unroll
    for (int m = 0; m < 4; ++m)
        #pragma unroll
        for (int r = 0; r < 4; ++r) {
            u32 a1 = k1[m][r], a2 = k2[m][r];
            #pragma unroll
            for (int mask = 1; mask <= 8; mask <<= 1) {
                const u32 o1 = __shfl_xor(a1, mask, 64);
                const u32 o2 = __shfl_xor(a2, mask, 64);
                const u32 hi = a1 > o1 ? a1 : o1;
                a1 = a1 < o1 ? a1 : o1;
                const u32 lo2 = o2 < a2 ? o2 : a2;
                a2 = hi < lo2 ? hi : lo2;
            }
            if (c == 0) {
                const int rowl = wr * 64 + m * 16 + g * 4 + r;
                red[rowl][wc * 2]     = a1;
                red[rowl][wc * 2 + 1] = a2;
            }
        }
    __syncthreads();

    // ---- per-row top-4 of the 8 wave-candidates + rescore-needed flag ----
    if (tid < 256) {
        u32 s0 = ~0u, s1 = ~0u, s2 = ~0u, s3 = ~0u;
        #pragma unroll
        for (int jj = 0; jj < 8; ++jj) {
            const u32 k = red[tid][jj];
            if (k < s0)      { s3 = s2; s2 = s1; s1 = s0; s0 = k; }
            else if (k < s1) { s3 = s2; s2 = s1; s1 = k; }
            else if (k < s2) { s3 = s2; s2 = k; }
            else if (k < s3) { s3 = k; }
        }
        const float f0 = __uint_as_float(s0 & 0xFFFFFC00u);
        const float f1 = __uint_as_float(s1 & 0xFFFFFC00u);
        red[tid][0] = s0 & 1023u;
        red[tid][1] = s1 & 1023u;
        red[tid][2] = s2 & 1023u;
        red[tid][3] = s3 & 1023u;
        red[tid][4] = (f1 - f0 <= MARGIN) ? 1u : 0u;
    }
    __syncthreads();

    // ---- fused exact rescore (fp64), margin-skipped; wave w: rows w*16.. ----
    {
        const int cand = lane >> 4;      // 0..3
        const int cg   = lane & 15;      // 16-float chunk of C_
        #pragma unroll 1
        for (int i = 0; i < 16; ++i) {
            const int rl = w * 16 + i;
            const int n  = n0 + rl;
            if (!red[rl][4]) {           // wave-uniform: approx winner exact
                if (lane == 0) {
                    const int win = (int)red[rl][0];
                    idx_f[(size_t)n * NQ + q] = (float)win;
                    idx_i[(size_t)n * NQ + q] = win;
                }
                continue;
            }
            const int bin = (int)red[rl][cand];
            const float* xr = x_t + (size_t)n * C_ + cg * 16;
            const float* cr = cb + ((size_t)(q * BINS + bin)) * C_ + cg * 16;
            double d = 0.0;
            #pragma unroll
            for (int u = 0; u < 4; ++u) {
                const float4 xv = *(const float4*)(xr + u * 4);
                const float4 cv = *(const float4*)(cr + u * 4);
                d += (double)xv.x * cv.x + (double)xv.y * cv.y
                   + (double)xv.z * cv.z + (double)xv.w * cv.w;
            }
            #pragma unroll
            for (int off = 8; off; off >>= 1) d += __shfl_down(d, off, 16);
            const double dist = c2d[q * BINS + bin] - 2.0 * d; // valid @ cand*16
            // FULL-WAVE uniform broadcasts (all 64 lanes active here):
            const double d0 = __shfl(dist,  0, 64);
            const double d1 = __shfl(dist, 16, 64);
            const double d2 = __shfl(dist, 32, 64);
            const double d3 = __shfl(dist, 48, 64);
            if (lane == 0) {
                const int b0 = (int)red[rl][0], b1 = (int)red[rl][1];
                const int b2 = (int)red[rl][2], b3 = (int)red[rl][3];
                double best = d0;
                int win = b0;
                if (d1 < best || (d1 == best && b1 < win)) { best = d1; win = b1; }
                if (d2 < best || (d2 == best && b2 < win)) { best = d2; win = b2; }
                if (d3 < best || (d3 == best && b3 < win)) { best = d3; win = b3; }
                idx_f[(size_t)n * NQ + q] = (float)win;
                idx_i[(size_t)n * NQ + q] = win;
            }
        }
    }
}

// ---------------- gather: q_ste output + loss ----------------------------
__global__ __launch_bounds__(256)
void gather_kernel(const float* __restrict__ x, const float* __restrict__ cb,
                   const int* __restrict__ idx_i, float* __restrict__ out,
                   float* __restrict__ loss) {
    __shared__ float ql[C_][17];
    const int blk = blockIdx.x;
    const int b   = blk >> 7;
    const int t0  = (blk & 127) << 4;
    const int tid = threadIdx.x;
    {
        const int c = tid;
        for (int nl = 0; nl < 16; ++nl) {
            const int n = b * T_ + t0 + nl;
            float acc = 0.f;
            #pragma unroll
            for (int qq = 0; qq < NQ; ++qq) {
                const int id = idx_i[(size_t)n * NQ + qq];
                acc += cb[((size_t)qq * BINS + id) * C_ + c];
            }
            ql[c][nl] = acc;
        }
    }
    __syncthreads();
    const int tx = tid & 15, ty = tid >> 4;
    float lsum = 0.f;
    for (int cg = 0; cg < 16; ++cg) {
        const int c = cg * 16 + ty;
        const size_t off = ((size_t)b * C_ + c) * T_ + t0 + tx;
        const float qv = ql[c][tx];
        const float xv = x[off];
        out[off] = qv;
        const float d = qv - xv;
        lsum += d * d;
    }
    #pragma unroll
    for (int off = 32; off; off >>= 1) lsum += __shfl_down(lsum, off, 64);
    if ((tid & 63) == 0)
        atomicAdd(loss, lsum * (2.0f / (float)(B_ * C_ * T_)));
}

extern "C" void kernel_launch(void* const* d_in, const int* in_sizes, int n_in,
                              void* d_out, int out_size, void* d_ws, size_t ws_size,
                              hipStream_t stream) {
    const float* x  = (const float*)d_in[0];
    const float* cb = (const float*)d_in[1];

    float* out   = (float*)d_out;
    float* idx_f = out + (size_t)B_ * C_ * T_;
    float* loss  = idx_f + (size_t)NROWS * NQ;

    char* ws = (char*)d_ws;
    f16*    xs    = (f16*)(ws + XS_OFF);
    f16*    cs    = (f16*)(ws + CS_OFF);
    float*  x_t   = (float*)(ws + XT_OFF);
    double* c2d   = (double*)(ws + C2D_OFF);
    float*  c2k   = (float*)(ws + C2K_OFF);
    int*    idx_i = (int*)(ws + IDXI_OFF);

    hipMemsetAsync(loss, 0, sizeof(float), stream);
    prep_all<<<3072, 256, 0, stream>>>(x, x_t, xs, cb, cs, c2d, c2k);
    dist_kernel<<<512, 1024, 0, stream>>>(xs, cs, c2k, x_t, cb, c2d,
                                          idx_f, idx_i);
    gather_kernel<<<B_ * (T_ / 16), 256, 0, stream>>>(x, cb, idx_i, out, loss);
}

// Round 15
// 215.109 us; speedup vs baseline: 4.1014x; 4.1014x over previous
//
#include <hip/hip_runtime.h>

typedef unsigned long long u64;
typedef unsigned int u32;
typedef _Float16 f16;
typedef f16 f16x8 __attribute__((ext_vector_type(8)));
typedef float f32x4 __attribute__((ext_vector_type(4)));

#define B_   8
#define C_   256
#define T_   2048
#define NQ   8
#define BINS 1024
#define NROWS (B_ * T_)          // 16384
#define KA   256                 // A: single fp16 limb (row-major [n][256])
#define KB   256                 // B: single fp16 limb (row-major [code][256])
#define NTILE 16                 // 1024 codes / 64 per tile
#define MARGIN 3.0f              // >> worst-case approx error (~0.6) + chop

// ---- workspace layout (bytes) ----
#define XS_OFF   ((size_t)0)                       // f16 [16384][256]   =  8388608
#define CS_OFF   ((size_t)8388608)                 // f16 [8192][256]    =  4194304
#define XT_OFF   ((size_t)12582912)                // f32 [16384][256]   = 16777216
#define C2D_OFF  ((size_t)29360128)                // f64 [8192]         =    65536
#define C2K_OFF  ((size_t)29425664)                // f32 [8192] biased  =    32768
#define IDXI_OFF ((size_t)29458432)                // i32 [131072]       =   524288

static __device__ __forceinline__ void gll16(const void* g, void* l) {
    __builtin_amdgcn_global_load_lds(
        (const __attribute__((address_space(1))) u32*)g,
        (__attribute__((address_space(3))) u32*)l, 16, 0, 0);
}

// ---------------- prep_all: x transpose+cast | cb cast+norms -------------
// grid 3072: bid<1024 -> prep_x tile; bid>=1024 -> prep_cb block (4 codes)
struct alignas(8) H4 { f16 v[4]; };
__global__ __launch_bounds__(256)
void prep_all(const float* __restrict__ x, float* __restrict__ x_t,
              f16* __restrict__ xs, const float* __restrict__ cb,
              f16* __restrict__ cs, double* __restrict__ c2d,
              float* __restrict__ c2k) {
    const int tid = threadIdx.x;
    const int bid = blockIdx.x;
    if (bid < 1024) {
        __shared__ float tile[64][65];
        const int b  = bid >> 7;
        const int c0 = ((bid >> 5) & 3) * 64;
        const int t0 = (bid & 31) * 64;
        {
            const int j = tid & 63, cg = tid >> 6;
            #pragma unroll
            for (int ii = 0; ii < 16; ++ii) {
                const int cl = cg * 16 + ii;
                tile[cl][j] = x[((size_t)(b * C_ + c0 + cl) * T_) + t0 + j];
            }
        }
        __syncthreads();
        {
            const int cl = tid & 63, tg = tid >> 6;
            #pragma unroll
            for (int jj = 0; jj < 16; ++jj) {
                const int tl = tg * 16 + jj;
                const float v = tile[cl][tl];
                const size_t n = (size_t)b * T_ + t0 + tl;
                x_t[n * C_ + c0 + cl] = v;
                xs[n * KA + c0 + cl]  = (f16)v;
            }
        }
    } else {
        const int w    = tid >> 6;
        const int lane = tid & 63;
        const int code = (bid - 1024) * 4 + w;
        const float4 v = *(const float4*)(cb + (size_t)code * C_ + lane * 4);
        H4 h;
        h.v[0] = (f16)v.x; h.v[1] = (f16)v.y;
        h.v[2] = (f16)v.z; h.v[3] = (f16)v.w;
        *(H4*)(cs + (size_t)code * KB + lane * 4) = h;
        double s = (double)v.x * v.x + (double)v.y * v.y +
                   (double)v.z * v.z + (double)v.w * v.w;
        #pragma unroll
        for (int off = 32; off; off >>= 1) s += __shfl_down(s, off, 64);
        if (lane == 0) {
            c2d[code] = s;                    // exact norm (fp64 rescore)
            c2k[code] = (float)s + 1000.0f;   // biased: sc = c2+1000-2xc > 0
        }
    }
}

// ---------------- dist v7 (r13, measured best): r8 GEMM + margin-skip ----
// grid = 128 rt x 8 q = 1024 blocks (bid&7 = q -> XCD-local codebook),
// 1024 threads = 16 waves (4 wr x 4 wc). Each wave: 32 rows x K=256 of A
// in regs (af[2][8] = 64 VGPR; 60 VGPR total -> 8 waves/SIMD, 2 blocks/CU).
// NOTE (r14 lesson): af[4] variants are VGPR-infeasible — launch_bounds'
// 2nd arg is min waves/SIMD (VGPR cap = 512/waves), so m_rep=4 spills.
// B streams thru 64-code LDS dbuf, 1 barrier/tile. Positive-biased
// float-bit keys (6 VALU/insert); per-row top-4 margin-skipped exact fp64
// rescore fused in-kernel (full-wave-uniform shfls).
__global__ __launch_bounds__(1024)
void dist_kernel(const f16* __restrict__ xs, const f16* __restrict__ cs,
                 const float* __restrict__ c2k, const float* __restrict__ x_t,
                 const float* __restrict__ cb, const double* __restrict__ c2d,
                 float* __restrict__ idx_f, int* __restrict__ idx_i) {
    __shared__ f16 Bs[2][64][256];       // 64 KB
    __shared__ u32 red[128][8];          // 4 KB ([0..3] bins / [4] flag)

    const int tid  = threadIdx.x;
    const int lane = tid & 63;
    const int w    = tid >> 6;           // 0..15
    const int wr   = w >> 2;             // 0..3 row group (32 rows each)
    const int wc   = w & 3;              // 0..3 code column (16 codes/tile)
    const int bid  = blockIdx.x;
    const int q    = bid & 7;
    const int rt   = bid >> 3;
    const int n0   = rt * 128;

    const int c = lane & 15;             // MFMA col / frag row
    const int g = lane >> 4;             // 0..3 k-group

    // ---- A fragments in registers: rows n0 + wr*32 + m*16 + c ----
    f16x8 af[2][8];
    {
        const f16* pa = xs + (size_t)(n0 + wr * 32 + c) * KA + g * 8;
        #pragma unroll
        for (int m = 0; m < 2; ++m)
            #pragma unroll
            for (int kk = 0; kk < 8; ++kk)
                af[m][kk] = *(const f16x8*)(pa + m * 16 * KA + kk * 32);
    }

    // ---- staging: 2 x gll16 per thread per tile ----
    const int crow  = tid >> 5;                    // 0..31 (i=0), +32 (i=1)
    const int slotl = (tid & 31) ^ (crow & 7);     // inverse-swizzled source
    const f16* pb = cs + (size_t)q * 1024 * KB;
    const int wbase = w * 512;                     // uniform dest (f16)

    #define STAGE(buf, t)                                                    \
        do {                                                                 \
            f16* b0 = &Bs[buf][0][0];                                        \
            const f16* s_ = pb + (size_t)((t) * 64 + crow) * KB + slotl * 8; \
            gll16(s_,            b0 + wbase);                                 \
            gll16(s_ + 32 * KB,  b0 + 8192 + wbase);                          \
        } while (0)

    // per-(thread,row) top-2 keys: rows (m, r)
    u32 k1[2][4], k2[2][4];
    #pragma unroll
    for (int m = 0; m < 2; ++m)
        #pragma unroll
        for (int r = 0; r < 4; ++r) { k1[m][r] = ~0u; k2[m][r] = ~0u; }

    const float* c2q = c2k + q * BINS;
    const int rowoff = (wc * 16 + c) * 256;        // B frag row base (f16)
    const int sw = c & 7;

    STAGE(0, 0);
    __syncthreads();

    #pragma unroll 1
    for (int t = 0; t < NTILE; ++t) {
        const int buf = t & 1;
        if (t < NTILE - 1) STAGE(buf ^ 1, t + 1);

        f32x4 acc[2];
        #pragma unroll
        for (int m = 0; m < 2; ++m) {
            f32x4 z = {0.f, 0.f, 0.f, 0.f};
            acc[m] = z;
        }

        const f16* bb = &Bs[buf][0][0] + rowoff;
        #pragma unroll
        for (int half = 0; half < 2; ++half) {
            f16x8 bg[4];
            #pragma unroll
            for (int k4 = 0; k4 < 4; ++k4) {
                const int kk = half * 4 + k4;
                bg[k4] = *(const f16x8*)(bb + ((kk * 4 + g) ^ sw) * 8);
            }
            #pragma unroll
            for (int k4 = 0; k4 < 4; ++k4)
                #pragma unroll
                for (int m = 0; m < 2; ++m)
                    acc[m] = __builtin_amdgcn_mfma_f32_16x16x32_f16(
                        af[m][half * 4 + k4], bg[k4], acc[m], 0, 0, 0);
        }

        // top-2 insert (6 VALU/score): positive floats -> bits monotone
        const int codeL = t * 64 + wc * 16 + c;
        const float cc = c2q[codeL];
        #pragma unroll
        for (int m = 0; m < 2; ++m)
            #pragma unroll
            for (int r = 0; r < 4; ++r) {
                const float sc = fmaf(-2.f, acc[m][r], cc);
                const u32 key = (__float_as_uint(sc) & 0xFFFFFC00u) | (u32)codeL;
                const u32 hi = k1[m][r] > key ? k1[m][r] : key;
                k1[m][r] = k1[m][r] < key ? k1[m][r] : key;
                k2[m][r] = k2[m][r] < hi ? k2[m][r] : hi;
            }

        __syncthreads();   // drains prefetch (vmcnt0) + publishes buf^1
    }
    #undef STAGE

    // ---- merge: 16 lanes (codes) per row -> wave top2 -> red ----
    #pragma unroll
    for (int m = 0; m < 2; ++m)
        #pragma unroll
        for (int r = 0; r < 4; ++r) {
            u32 a1 = k1[m][r], a2 = k2[m][r];
            #pragma unroll
            for (int mask = 1; mask <= 8; mask <<= 1) {
                const u32 o1 = __shfl_xor(a1, mask, 64);
                const u32 o2 = __shfl_xor(a2, mask, 64);
                const u32 hi = a1 > o1 ? a1 : o1;
                a1 = a1 < o1 ? a1 : o1;
                const u32 lo2 = o2 < a2 ? o2 : a2;
                a2 = hi < lo2 ? hi : lo2;
            }
            if (c == 0) {
                const int rowl = wr * 32 + m * 16 + g * 4 + r;
                red[rowl][wc * 2]     = a1;
                red[rowl][wc * 2 + 1] = a2;
            }
        }
    __syncthreads();

    // ---- per-row top-4 of the 8 wave-candidates + rescore-needed flag ----
    if (tid < 128) {
        u32 s0 = ~0u, s1 = ~0u, s2 = ~0u, s3 = ~0u;
        #pragma unroll
        for (int jj = 0; jj < 8; ++jj) {
            const u32 k = red[tid][jj];
            if (k < s0)      { s3 = s2; s2 = s1; s1 = s0; s0 = k; }
            else if (k < s1) { s3 = s2; s2 = s1; s1 = k; }
            else if (k < s2) { s3 = s2; s2 = k; }
            else if (k < s3) { s3 = k; }
        }
        const float f0 = __uint_as_float(s0 & 0xFFFFFC00u);
        const float f1 = __uint_as_float(s1 & 0xFFFFFC00u);
        red[tid][0] = s0 & 1023u;
        red[tid][1] = s1 & 1023u;
        red[tid][2] = s2 & 1023u;
        red[tid][3] = s3 & 1023u;
        red[tid][4] = (f1 - f0 <= MARGIN) ? 1u : 0u;
    }
    __syncthreads();

    // ---- fused exact rescore (fp64), margin-skipped; wave w: rows w*8.. ----
    {
        const int cand = lane >> 4;      // 0..3
        const int cg   = lane & 15;      // 16-float chunk of C_
        #pragma unroll 1
        for (int i = 0; i < 8; ++i) {
            const int rl = w * 8 + i;
            const int n  = n0 + rl;
            if (!red[rl][4]) {           // wave-uniform: approx winner exact
                if (lane == 0) {
                    const int win = (int)red[rl][0];
                    idx_f[(size_t)n * NQ + q] = (float)win;
                    idx_i[(size_t)n * NQ + q] = win;
                }
                continue;
            }
            const int bin = (int)red[rl][cand];
            const float* xr = x_t + (size_t)n * C_ + cg * 16;
            const float* cr = cb + ((size_t)(q * BINS + bin)) * C_ + cg * 16;
            double d = 0.0;
            #pragma unroll
            for (int u = 0; u < 4; ++u) {
                const float4 xv = *(const float4*)(xr + u * 4);
                const float4 cv = *(const float4*)(cr + u * 4);
                d += (double)xv.x * cv.x + (double)xv.y * cv.y
                   + (double)xv.z * cv.z + (double)xv.w * cv.w;
            }
            #pragma unroll
            for (int off = 8; off; off >>= 1) d += __shfl_down(d, off, 16);
            const double dist = c2d[q * BINS + bin] - 2.0 * d; // valid @ cand*16
            // FULL-WAVE uniform broadcasts (all 64 lanes active here):
            const double d0 = __shfl(dist,  0, 64);
            const double d1 = __shfl(dist, 16, 64);
            const double d2 = __shfl(dist, 32, 64);
            const double d3 = __shfl(dist, 48, 64);
            if (lane == 0) {
                const int b0 = (int)red[rl][0], b1 = (int)red[rl][1];
                const int b2 = (int)red[rl][2], b3 = (int)red[rl][3];
                double best = d0;
                int win = b0;
                if (d1 < best || (d1 == best && b1 < win)) { best = d1; win = b1; }
                if (d2 < best || (d2 == best && b2 < win)) { best = d2; win = b2; }
                if (d3 < best || (d3 == best && b3 < win)) { best = d3; win = b3; }
                idx_f[(size_t)n * NQ + q] = (float)win;
                idx_i[(size_t)n * NQ + q] = win;
            }
        }
    }
}

// ---------------- gather: q_ste output + loss ----------------------------
__global__ __launch_bounds__(256)
void gather_kernel(const float* __restrict__ x, const float* __restrict__ cb,
                   const int* __restrict__ idx_i, float* __restrict__ out,
                   float* __restrict__ loss) {
    __shared__ float ql[C_][17];
    const int blk = blockIdx.x;
    const int b   = blk >> 7;
    const int t0  = (blk & 127) << 4;
    const int tid = threadIdx.x;
    {
        const int c = tid;
        for (int nl = 0; nl < 16; ++nl) {
            const int n = b * T_ + t0 + nl;
            float acc = 0.f;
            #pragma unroll
            for (int qq = 0; qq < NQ; ++qq) {
                const int id = idx_i[(size_t)n * NQ + qq];
                acc += cb[((size_t)qq * BINS + id) * C_ + c];
            }
            ql[c][nl] = acc;
        }
    }
    __syncthreads();
    const int tx = tid & 15, ty = tid >> 4;
    float lsum = 0.f;
    for (int cg = 0; cg < 16; ++cg) {
        const int c = cg * 16 + ty;
        const size_t off = ((size_t)b * C_ + c) * T_ + t0 + tx;
        const float qv = ql[c][tx];
        const float xv = x[off];
        out[off] = qv;
        const float d = qv - xv;
        lsum += d * d;
    }
    #pragma unroll
    for (int off = 32; off; off >>= 1) lsum += __shfl_down(lsum, off, 64);
    if ((tid & 63) == 0)
        atomicAdd(loss, lsum * (2.0f / (float)(B_ * C_ * T_)));
}

extern "C" void kernel_launch(void* const* d_in, const int* in_sizes, int n_in,
                              void* d_out, int out_size, void* d_ws, size_t ws_size,
                              hipStream_t stream) {
    const float* x  = (const float*)d_in[0];
    const float* cb = (const float*)d_in[1];

    float* out   = (float*)d_out;
    float* idx_f = out + (size_t)B_ * C_ * T_;
    float* loss  = idx_f + (size_t)NROWS * NQ;

    char* ws = (char*)d_ws;
    f16*    xs    = (f16*)(ws + XS_OFF);
    f16*    cs    = (f16*)(ws + CS_OFF);
    float*  x_t   = (float*)(ws + XT_OFF);
    double* c2d   = (double*)(ws + C2D_OFF);
    float*  c2k   = (float*)(ws + C2K_OFF);
    int*    idx_i = (int*)(ws + IDXI_OFF);

    hipMemsetAsync(loss, 0, sizeof(float), stream);
    prep_all<<<3072, 256, 0, stream>>>(x, x_t, xs, cb, cs, c2d, c2k);
    dist_kernel<<<1024, 1024, 0, stream>>>(xs, cs, c2k, x_t, cb, c2d,
                                           idx_f, idx_i);
    gather_kernel<<<B_ * (T_ / 16), 256, 0, stream>>>(x, cb, idx_i, out, loss);
}

// Round 16
// 215.100 us; speedup vs baseline: 4.1016x; 1.0000x over previous
//
#include <hip/hip_runtime.h>

typedef unsigned long long u64;
typedef unsigned int u32;
typedef _Float16 f16;
typedef f16 f16x8 __attribute__((ext_vector_type(8)));
typedef float f32x4 __attribute__((ext_vector_type(4)));

#define B_   8
#define C_   256
#define T_   2048
#define NQ   8
#define BINS 1024
#define NROWS (B_ * T_)          // 16384
#define KA   256                 // A: single fp16 limb (row-major [n][256])
#define KB   256                 // B: single fp16 limb (row-major [code][256])
#define NTILE 16                 // 1024 codes / 64 per tile
#define MARGIN 3.0f              // >> worst-case approx error (~0.6) + chop

// ---- workspace layout (bytes) ----
#define XS_OFF   ((size_t)0)                       // f16 [16384][256]   =  8388608
#define CS_OFF   ((size_t)8388608)                 // f16 [8192][256]    =  4194304
#define XT_OFF   ((size_t)12582912)                // f32 [16384][256]   = 16777216
#define C2D_OFF  ((size_t)29360128)                // f64 [8192]         =    65536
#define C2K_OFF  ((size_t)29425664)                // f32 [8192] biased  =    32768
#define IDXI_OFF ((size_t)29458432)                // i32 [131072]       =   524288

static __device__ __forceinline__ void gll16(const void* g, void* l) {
    __builtin_amdgcn_global_load_lds(
        (const __attribute__((address_space(1))) u32*)g,
        (__attribute__((address_space(3))) u32*)l, 16, 0, 0);
}

// ---------------- prep_all: x transpose+cast | cb cast+norms -------------
// grid 3072: bid<1024 -> prep_x tile; bid>=1024 -> prep_cb block (4 codes)
struct alignas(8) H4 { f16 v[4]; };
__global__ __launch_bounds__(256)
void prep_all(const float* __restrict__ x, float* __restrict__ x_t,
              f16* __restrict__ xs, const float* __restrict__ cb,
              f16* __restrict__ cs, double* __restrict__ c2d,
              float* __restrict__ c2k) {
    const int tid = threadIdx.x;
    const int bid = blockIdx.x;
    if (bid < 1024) {
        __shared__ float tile[64][65];
        const int b  = bid >> 7;
        const int c0 = ((bid >> 5) & 3) * 64;
        const int t0 = (bid & 31) * 64;
        {
            const int j = tid & 63, cg = tid >> 6;
            #pragma unroll
            for (int ii = 0; ii < 16; ++ii) {
                const int cl = cg * 16 + ii;
                tile[cl][j] = x[((size_t)(b * C_ + c0 + cl) * T_) + t0 + j];
            }
        }
        __syncthreads();
        {
            const int cl = tid & 63, tg = tid >> 6;
            #pragma unroll
            for (int jj = 0; jj < 16; ++jj) {
                const int tl = tg * 16 + jj;
                const float v = tile[cl][tl];
                const size_t n = (size_t)b * T_ + t0 + tl;
                x_t[n * C_ + c0 + cl] = v;
                xs[n * KA + c0 + cl]  = (f16)v;
            }
        }
    } else {
        const int w    = tid >> 6;
        const int lane = tid & 63;
        const int code = (bid - 1024) * 4 + w;
        const float4 v = *(const float4*)(cb + (size_t)code * C_ + lane * 4);
        H4 h;
        h.v[0] = (f16)v.x; h.v[1] = (f16)v.y;
        h.v[2] = (f16)v.z; h.v[3] = (f16)v.w;
        *(H4*)(cs + (size_t)code * KB + lane * 4) = h;
        double s = (double)v.x * v.x + (double)v.y * v.y +
                   (double)v.z * v.z + (double)v.w * v.w;
        #pragma unroll
        for (int off = 32; off; off >>= 1) s += __shfl_down(s, off, 64);
        if (lane == 0) {
            c2d[code] = s;                    // exact norm (fp64 rescore)
            c2k[code] = (float)s + 1000.0f;   // biased: sc = c2+1000-2xc > 0
        }
    }
}

// ---------------- dist v9: r13 GEMM + XCD-locality bid remap -------------
// grid = 1024 blocks. r16 change: q = bid>>7, rt = bid&127 (was q=bid&7).
// XCD k now receives bids === k (mod 8) -> a FIXED set of 16 rt values
// reused across all 8 q-phases: per-XCD L2 working set = 1 MB xs
// (resident, 8x reuse) + 0.5 MB cs per phase, vs 8.4 MB xs zero-reuse
// before (FETCH 61 MB). 1024 threads = 16 waves (4 wr x 4 wc); A 32 rows
// in regs (af[2][8], 60 VGPR -> 8 waves/SIMD, 2 blocks/CU). B streams
// thru 64-code LDS dbuf, 1 barrier/tile. Positive-biased float-bit keys;
// per-row top-4 margin-skipped exact fp64 rescore fused in-kernel.
__global__ __launch_bounds__(1024)
void dist_kernel(const f16* __restrict__ xs, const f16* __restrict__ cs,
                 const float* __restrict__ c2k, const float* __restrict__ x_t,
                 const float* __restrict__ cb, const double* __restrict__ c2d,
                 float* __restrict__ idx_f, int* __restrict__ idx_i) {
    __shared__ f16 Bs[2][64][256];       // 64 KB
    __shared__ u32 red[128][8];          // 4 KB ([0..3] bins / [4] flag)

    const int tid  = threadIdx.x;
    const int lane = tid & 63;
    const int w    = tid >> 6;           // 0..15
    const int wr   = w >> 2;             // 0..3 row group (32 rows each)
    const int wc   = w & 3;              // 0..3 code column (16 codes/tile)
    const int bid  = blockIdx.x;
    const int q    = bid >> 7;           // r16: q outer -> XCD keeps rt set
    const int rt   = bid & 127;
    const int n0   = rt * 128;

    const int c = lane & 15;             // MFMA col / frag row
    const int g = lane >> 4;             // 0..3 k-group

    // ---- A fragments in registers: rows n0 + wr*32 + m*16 + c ----
    f16x8 af[2][8];
    {
        const f16* pa = xs + (size_t)(n0 + wr * 32 + c) * KA + g * 8;
        #pragma unroll
        for (int m = 0; m < 2; ++m)
            #pragma unroll
            for (int kk = 0; kk < 8; ++kk)
                af[m][kk] = *(const f16x8*)(pa + m * 16 * KA + kk * 32);
    }

    // ---- staging: 2 x gll16 per thread per tile ----
    const int crow  = tid >> 5;                    // 0..31 (i=0), +32 (i=1)
    const int slotl = (tid & 31) ^ (crow & 7);     // inverse-swizzled source
    const f16* pb = cs + (size_t)q * 1024 * KB;
    const int wbase = w * 512;                     // uniform dest (f16)

    #define STAGE(buf, t)                                                    \
        do {                                                                 \
            f16* b0 = &Bs[buf][0][0];                                        \
            const f16* s_ = pb + (size_t)((t) * 64 + crow) * KB + slotl * 8; \
            gll16(s_,            b0 + wbase);                                 \
            gll16(s_ + 32 * KB,  b0 + 8192 + wbase);                          \
        } while (0)

    // per-(thread,row) top-2 keys: rows (m, r)
    u32 k1[2][4], k2[2][4];
    #pragma unroll
    for (int m = 0; m < 2; ++m)
        #pragma unroll
        for (int r = 0; r < 4; ++r) { k1[m][r] = ~0u; k2[m][r] = ~0u; }

    const float* c2q = c2k + q * BINS;
    const int rowoff = (wc * 16 + c) * 256;        // B frag row base (f16)
    const int sw = c & 7;

    STAGE(0, 0);
    __syncthreads();

    #pragma unroll 1
    for (int t = 0; t < NTILE; ++t) {
        const int buf = t & 1;
        if (t < NTILE - 1) STAGE(buf ^ 1, t + 1);

        f32x4 acc[2];
        #pragma unroll
        for (int m = 0; m < 2; ++m) {
            f32x4 z = {0.f, 0.f, 0.f, 0.f};
            acc[m] = z;
        }

        const f16* bb = &Bs[buf][0][0] + rowoff;
        #pragma unroll
        for (int half = 0; half < 2; ++half) {
            f16x8 bg[4];
            #pragma unroll
            for (int k4 = 0; k4 < 4; ++k4) {
                const int kk = half * 4 + k4;
                bg[k4] = *(const f16x8*)(bb + ((kk * 4 + g) ^ sw) * 8);
            }
            #pragma unroll
            for (int k4 = 0; k4 < 4; ++k4)
                #pragma unroll
                for (int m = 0; m < 2; ++m)
                    acc[m] = __builtin_amdgcn_mfma_f32_16x16x32_f16(
                        af[m][half * 4 + k4], bg[k4], acc[m], 0, 0, 0);
        }

        // top-2 insert (6 VALU/score): positive floats -> bits monotone
        const int codeL = t * 64 + wc * 16 + c;
        const float cc = c2q[codeL];
        #pragma unroll
        for (int m = 0; m < 2; ++m)
            #pragma unroll
            for (int r = 0; r < 4; ++r) {
                const float sc = fmaf(-2.f, acc[m][r], cc);
                const u32 key = (__float_as_uint(sc) & 0xFFFFFC00u) | (u32)codeL;
                const u32 hi = k1[m][r] > key ? k1[m][r] : key;
                k1[m][r] = k1[m][r] < key ? k1[m][r] : key;
                k2[m][r] = k2[m][r] < hi ? k2[m][r] : hi;
            }

        __syncthreads();   // drains prefetch (vmcnt0) + publishes buf^1
    }
    #undef STAGE

    // ---- merge: 16 lanes (codes) per row -> wave top2 -> red ----
    #pragma unroll
    for (int m = 0; m < 2; ++m)
        #pragma unroll
        for (int r = 0; r < 4; ++r) {
            u32 a1 = k1[m][r], a2 = k2[m][r];
            #pragma unroll
            for (int mask = 1; mask <= 8; mask <<= 1) {
                const u32 o1 = __shfl_xor(a1, mask, 64);
                const u32 o2 = __shfl_xor(a2, mask, 64);
                const u32 hi = a1 > o1 ? a1 : o1;
                a1 = a1 < o1 ? a1 : o1;
                const u32 lo2 = o2 < a2 ? o2 : a2;
                a2 = hi < lo2 ? hi : lo2;
            }
            if (c == 0) {
                const int rowl = wr * 32 + m * 16 + g * 4 + r;
                red[rowl][wc * 2]     = a1;
                red[rowl][wc * 2 + 1] = a2;
            }
        }
    __syncthreads();

    // ---- per-row top-4 of the 8 wave-candidates + rescore-needed flag ----
    if (tid < 128) {
        u32 s0 = ~0u, s1 = ~0u, s2 = ~0u, s3 = ~0u;
        #pragma unroll
        for (int jj = 0; jj < 8; ++jj) {
            const u32 k = red[tid][jj];
            if (k < s0)      { s3 = s2; s2 = s1; s1 = s0; s0 = k; }
            else if (k < s1) { s3 = s2; s2 = s1; s1 = k; }
            else if (k < s2) { s3 = s2; s2 = k; }
            else if (k < s3) { s3 = k; }
        }
        const float f0 = __uint_as_float(s0 & 0xFFFFFC00u);
        const float f1 = __uint_as_float(s1 & 0xFFFFFC00u);
        red[tid][0] = s0 & 1023u;
        red[tid][1] = s1 & 1023u;
        red[tid][2] = s2 & 1023u;
        red[tid][3] = s3 & 1023u;
        red[tid][4] = (f1 - f0 <= MARGIN) ? 1u : 0u;
    }
    __syncthreads();

    // ---- fused exact rescore (fp64), margin-skipped; wave w: rows w*8.. ----
    {
        const int cand = lane >> 4;      // 0..3
        const int cg   = lane & 15;      // 16-float chunk of C_
        #pragma unroll 1
        for (int i = 0; i < 8; ++i) {
            const int rl = w * 8 + i;
            const int n  = n0 + rl;
            if (!red[rl][4]) {           // wave-uniform: approx winner exact
                if (lane == 0) {
                    const int win = (int)red[rl][0];
                    idx_f[(size_t)n * NQ + q] = (float)win;
                    idx_i[(size_t)n * NQ + q] = win;
                }
                continue;
            }
            const int bin = (int)red[rl][cand];
            const float* xr = x_t + (size_t)n * C_ + cg * 16;
            const float* cr = cb + ((size_t)(q * BINS + bin)) * C_ + cg * 16;
            double d = 0.0;
            #pragma unroll
            for (int u = 0; u < 4; ++u) {
                const float4 xv = *(const float4*)(xr + u * 4);
                const float4 cv = *(const float4*)(cr + u * 4);
                d += (double)xv.x * cv.x + (double)xv.y * cv.y
                   + (double)xv.z * cv.z + (double)xv.w * cv.w;
            }
            #pragma unroll
            for (int off = 8; off; off >>= 1) d += __shfl_down(d, off, 16);
            const double dist = c2d[q * BINS + bin] - 2.0 * d; // valid @ cand*16
            // FULL-WAVE uniform broadcasts (all 64 lanes active here):
            const double d0 = __shfl(dist,  0, 64);
            const double d1 = __shfl(dist, 16, 64);
            const double d2 = __shfl(dist, 32, 64);
            const double d3 = __shfl(dist, 48, 64);
            if (lane == 0) {
                const int b0 = (int)red[rl][0], b1 = (int)red[rl][1];
                const int b2 = (int)red[rl][2], b3 = (int)red[rl][3];
                double best = d0;
                int win = b0;
                if (d1 < best || (d1 == best && b1 < win)) { best = d1; win = b1; }
                if (d2 < best || (d2 == best && b2 < win)) { best = d2; win = b2; }
                if (d3 < best || (d3 == best && b3 < win)) { best = d3; win = b3; }
                idx_f[(size_t)n * NQ + q] = (float)win;
                idx_i[(size_t)n * NQ + q] = win;
            }
        }
    }
}

// ---------------- gather: q_ste output + loss ----------------------------
__global__ __launch_bounds__(256)
void gather_kernel(const float* __restrict__ x, const float* __restrict__ cb,
                   const int* __restrict__ idx_i, float* __restrict__ out,
                   float* __restrict__ loss) {
    __shared__ float ql[C_][17];
    const int blk = blockIdx.x;
    const int b   = blk >> 7;
    const int t0  = (blk & 127) << 4;
    const int tid = threadIdx.x;
    {
        const int c = tid;
        for (int nl = 0; nl < 16; ++nl) {
            const int n = b * T_ + t0 + nl;
            float acc = 0.f;
            #pragma unroll
            for (int qq = 0; qq < NQ; ++qq) {
                const int id = idx_i[(size_t)n * NQ + qq];
                acc += cb[((size_t)qq * BINS + id) * C_ + c];
            }
            ql[c][nl] = acc;
        }
    }
    __syncthreads();
    const int tx = tid & 15, ty = tid >> 4;
    float lsum = 0.f;
    for (int cg = 0; cg < 16; ++cg) {
        const int c = cg * 16 + ty;
        const size_t off = ((size_t)b * C_ + c) * T_ + t0 + tx;
        const float qv = ql[c][tx];
        const float xv = x[off];
        out[off] = qv;
        const float d = qv - xv;
        lsum += d * d;
    }
    #pragma unroll
    for (int off = 32; off; off >>= 1) lsum += __shfl_down(lsum, off, 64);
    if ((tid & 63) == 0)
        atomicAdd(loss, lsum * (2.0f / (float)(B_ * C_ * T_)));
}

extern "C" void kernel_launch(void* const* d_in, const int* in_sizes, int n_in,
                              void* d_out, int out_size, void* d_ws, size_t ws_size,
                              hipStream_t stream) {
    const float* x  = (const float*)d_in[0];
    const float* cb = (const float*)d_in[1];

    float* out   = (float*)d_out;
    float* idx_f = out + (size_t)B_ * C_ * T_;
    float* loss  = idx_f + (size_t)NROWS * NQ;

    char* ws = (char*)d_ws;
    f16*    xs    = (f16*)(ws + XS_OFF);
    f16*    cs    = (f16*)(ws + CS_OFF);
    float*  x_t   = (float*)(ws + XT_OFF);
    double* c2d   = (double*)(ws + C2D_OFF);
    float*  c2k   = (float*)(ws + C2K_OFF);
    int*    idx_i = (int*)(ws + IDXI_OFF);

    hipMemsetAsync(loss, 0, sizeof(float), stream);
    prep_all<<<3072, 256, 0, stream>>>(x, x_t, xs, cb, cs, c2d, c2k);
    dist_kernel<<<1024, 1024, 0, stream>>>(xs, cs, c2k, x_t, cb, c2d,
                                           idx_f, idx_i);
    gather_kernel<<<B_ * (T_ / 16), 256, 0, stream>>>(x, cb, idx_i, out, loss);
}